// Round 1
// baseline (573.276 us; speedup 1.0000x reference)
//
#include <hip/hip_runtime.h>
#include <hip/hip_fp16.h>

#define NODES_PER_BLOCK 64      // mm1 tile

__global__ void zero_i_kernel(int* __restrict__ p, int total) {
  int i = blockIdx.x * blockDim.x + threadIdx.x;
  if (i < total) p[i] = 0;
}

// in-degree histogram over targets; deg[] is 400 KB -> L2-resident, low contention
__global__ __launch_bounds__(256) void histN_kernel(const int* __restrict__ col,
                                                    int* __restrict__ deg, int e) {
  int stride = gridDim.x * 256;
  int i = blockIdx.x * 256 + threadIdx.x;
  int e4 = e >> 2;
  for (int v = i; v < e4; v += stride) {
    int4 c = ((const int4*)col)[v];
    atomicAdd(&deg[c.x], 1);
    atomicAdd(&deg[c.y], 1);
    atomicAdd(&deg[c.z], 1);
    atomicAdd(&deg[c.w], 1);
  }
  for (int v = (e4 << 2) + i; v < e; v += stride) atomicAdd(&deg[col[v]], 1);
}

// block-local exclusive scan of deg -> node_start (partial), block totals -> bsum
__global__ __launch_bounds__(1024) void scan1_kernel(const int* __restrict__ deg,
                                                     int* __restrict__ node_start,
                                                     int* __restrict__ bsum, int n) {
  __shared__ int lds[1024];
  int t = threadIdx.x;
  int i = blockIdx.x * 1024 + t;
  int v = (i < n) ? deg[i] : 0;
  lds[t] = v;
  __syncthreads();
  for (int off = 1; off < 1024; off <<= 1) {
    int u = (t >= off) ? lds[t - off] : 0;
    __syncthreads();
    lds[t] += u;
    __syncthreads();
  }
  if (i < n) node_start[i] = lds[t] - v;
  if (t == 1023) bsum[blockIdx.x] = lds[1023];
}

// exclusive scan of block totals in place (nb <= 1024)
__global__ __launch_bounds__(1024) void scan2_kernel(int* __restrict__ bsum, int nb) {
  __shared__ int lds[1024];
  int t = threadIdx.x;
  int v = (t < nb) ? bsum[t] : 0;
  lds[t] = v;
  __syncthreads();
  for (int off = 1; off < 1024; off <<= 1) {
    int u = (t >= off) ? lds[t - off] : 0;
    __syncthreads();
    lds[t] += u;
    __syncthreads();
  }
  if (t < nb) bsum[t] = lds[t] - v;
}

// finalize: add block offsets, copy cursor array, dinv, sentinel
__global__ __launch_bounds__(1024) void scan3_kernel(int* __restrict__ node_start,
                                                     const int* __restrict__ bsum,
                                                     const int* __restrict__ deg,
                                                     int* __restrict__ cur,
                                                     float* __restrict__ dinv,
                                                     int n, int e) {
  int i = blockIdx.x * 1024 + threadIdx.x;
  if (i < n) {
    int s = node_start[i] + bsum[blockIdx.x];
    node_start[i] = s;
    cur[i] = s;
    dinv[i] = rsqrtf((float)deg[i] + 1.0f);
  } else if (i == n) {
    node_start[n] = e;
  }
}

// one-pass counting-sort scatter: pairs grouped by target node.
// Within-group order is arbitrary (aggregation is a sum). 3125 blocks -> latency hidden.
__global__ __launch_bounds__(256) void scatter_kernel(const int* __restrict__ row,
                                                      const int* __restrict__ col,
                                                      int* __restrict__ cur,
                                                      int* __restrict__ pairs, int e) {
  int stride = gridDim.x * 256;
  int i = blockIdx.x * 256 + threadIdx.x;
  int e4 = e >> 2;
  for (int v = i; v < e4; v += stride) {
    int4 c = ((const int4*)col)[v];
    int4 r = ((const int4*)row)[v];
    pairs[atomicAdd(&cur[c.x], 1)] = r.x;
    pairs[atomicAdd(&cur[c.y], 1)] = r.y;
    pairs[atomicAdd(&cur[c.z], 1)] = r.z;
    pairs[atomicAdd(&cur[c.w], 1)] = r.w;
  }
  for (int v = (e4 << 2) + i; v < e; v += stride) {
    pairs[atomicAdd(&cur[col[v]], 1)] = row[v];
  }
}

// s1 = fp16( (x @ W1) * dinv ) ; 32 B/row -> L2-resident table
__global__ __launch_bounds__(256) void mm1_kernel(const float* __restrict__ x,
                                                  const float* __restrict__ W1,
                                                  const float* __restrict__ dinv,
                                                  __half* __restrict__ s1, int n) {
  __shared__ float xs[NODES_PER_BLOCK][129];
  __shared__ float ws[128 * 16];
  int t = threadIdx.x;
  for (int i = t; i < 128 * 16; i += 256) ws[i] = W1[i];
  int base = blockIdx.x * NODES_PER_BLOCK;
  for (int i = t * 4; i < NODES_PER_BLOCK * 128; i += 256 * 4) {
    int nn = i >> 7, k = i & 127;
    if (base + nn < n) {
      float4 v = *(const float4*)(x + (size_t)(base + nn) * 128 + k);
      xs[nn][k] = v.x; xs[nn][k + 1] = v.y; xs[nn][k + 2] = v.z; xs[nn][k + 3] = v.w;
    }
  }
  __syncthreads();
  int nn = t >> 2;
  int j0 = (t & 3) * 4;
  float a0 = 0, a1 = 0, a2 = 0, a3 = 0;
  #pragma unroll 8
  for (int k = 0; k < 128; k++) {
    float xv = xs[nn][k];
    const float* wr = ws + k * 16 + j0;
    a0 += xv * wr[0]; a1 += xv * wr[1]; a2 += xv * wr[2]; a3 += xv * wr[3];
  }
  int node = base + nn;
  if (node < n) {
    float d = dinv[node];
    __half2 p0 = __floats2half2_rn(a0 * d, a1 * d);
    __half2 p1 = __floats2half2_rn(a2 * d, a3 * d);
    union { struct { __half2 a, b; } h; uint2 u; } pk;
    pk.h.a = p0; pk.h.b = p1;
    *(uint2*)(s1 + (size_t)node * 16 + j0) = pk.u;
  }
}

union H4 { float2 f2; __half2 h2[2]; };

__device__ __forceinline__ void acc_h4(const __half* __restrict__ tbl, int src, int q,
                                       float& a0, float& a1, float& a2, float& a3) {
  H4 w; w.f2 = *(const float2*)(tbl + (size_t)src * 16 + 4 * q);
  float2 l = __half22float2(w.h2[0]), h = __half22float2(w.h2[1]);
  a0 += l.x; a1 += l.y; a2 += h.x; a3 += h.y;
}

// layer-1: contiguous-run register aggregation + fused relu/bias/rescale
__global__ __launch_bounds__(512) void agg1_kernel(const int* __restrict__ pairs,
                                                   const int* __restrict__ node_start,
                                                   const __half* __restrict__ s1,
                                                   const float* __restrict__ dinv,
                                                   const float* __restrict__ b1,
                                                   __half* __restrict__ s2, int n) {
  __shared__ float lb1[16];
  int t = threadIdx.x;
  if (t < 16) lb1[t] = b1[t];
  __syncthreads();
  int node = blockIdx.x * 128 + (t >> 2);
  int q = t & 3;             // feature quad (4 halfs = 8 B)
  if (node >= n) return;     // no barriers after this point
  H4 u; u.f2 = *(const float2*)(s1 + (size_t)node * 16 + 4 * q);  // self loop
  float2 lo = __half22float2(u.h2[0]), hi = __half22float2(u.h2[1]);
  float a0 = lo.x, a1 = lo.y, a2 = hi.x, a3 = hi.y;
  int j = node_start[node], en = node_start[node + 1];
  for (; j + 7 < en; j += 8) {
    int p0 = pairs[j],     p1 = pairs[j + 1], p2 = pairs[j + 2], p3 = pairs[j + 3];
    int p4 = pairs[j + 4], p5 = pairs[j + 5], p6 = pairs[j + 6], p7 = pairs[j + 7];
    acc_h4(s1, p0, q, a0, a1, a2, a3); acc_h4(s1, p1, q, a0, a1, a2, a3);
    acc_h4(s1, p2, q, a0, a1, a2, a3); acc_h4(s1, p3, q, a0, a1, a2, a3);
    acc_h4(s1, p4, q, a0, a1, a2, a3); acc_h4(s1, p5, q, a0, a1, a2, a3);
    acc_h4(s1, p6, q, a0, a1, a2, a3); acc_h4(s1, p7, q, a0, a1, a2, a3);
  }
  for (; j < en; j++) acc_h4(s1, pairs[j], q, a0, a1, a2, a3);
  float d = dinv[node];
  int f = 4 * q;
  a0 = fmaxf(fmaf(d, a0, lb1[f + 0]), 0.f) * d;
  a1 = fmaxf(fmaf(d, a1, lb1[f + 1]), 0.f) * d;
  a2 = fmaxf(fmaf(d, a2, lb1[f + 2]), 0.f) * d;
  a3 = fmaxf(fmaf(d, a3, lb1[f + 3]), 0.f) * d;
  H4 o; o.h2[0] = __floats2half2_rn(a0, a1); o.h2[1] = __floats2half2_rn(a2, a3);
  *(float2*)(s2 + (size_t)node * 16 + 4 * q) = o.f2;
}

// layer-2: contiguous-run aggregation + fused 16->64 transform -> out (fp32)
__global__ __launch_bounds__(512) void agg2_kernel(const int* __restrict__ pairs,
                                                   const int* __restrict__ node_start,
                                                   const __half* __restrict__ s2,
                                                   const float* __restrict__ dinv,
                                                   const float* __restrict__ W2,
                                                   const float* __restrict__ b2,
                                                   float* __restrict__ out, int n) {
  __shared__ float tile[128 * 16];   // pre-activation (exact ownership, no atomics)
  __shared__ float w2s[16 * 64];
  __shared__ float b2s[64];
  int t = threadIdx.x;
  for (int i = t; i < 16 * 64; i += 512) w2s[i] = W2[i];
  if (t < 64) b2s[t] = b2[t];
  int node_l = t >> 2;
  int q = t & 3;
  int node = blockIdx.x * 128 + node_l;
  if (node < n) {
    H4 u; u.f2 = *(const float2*)(s2 + (size_t)node * 16 + 4 * q);  // self loop
    float2 lo = __half22float2(u.h2[0]), hi = __half22float2(u.h2[1]);
    float a0 = lo.x, a1 = lo.y, a2 = hi.x, a3 = hi.y;
    int j = node_start[node], en = node_start[node + 1];
    for (; j + 7 < en; j += 8) {
      int p0 = pairs[j],     p1 = pairs[j + 1], p2 = pairs[j + 2], p3 = pairs[j + 3];
      int p4 = pairs[j + 4], p5 = pairs[j + 5], p6 = pairs[j + 6], p7 = pairs[j + 7];
      acc_h4(s2, p0, q, a0, a1, a2, a3); acc_h4(s2, p1, q, a0, a1, a2, a3);
      acc_h4(s2, p2, q, a0, a1, a2, a3); acc_h4(s2, p3, q, a0, a1, a2, a3);
      acc_h4(s2, p4, q, a0, a1, a2, a3); acc_h4(s2, p5, q, a0, a1, a2, a3);
      acc_h4(s2, p6, q, a0, a1, a2, a3); acc_h4(s2, p7, q, a0, a1, a2, a3);
    }
    for (; j < en; j++) acc_h4(s2, pairs[j], q, a0, a1, a2, a3);
    float d = dinv[node];
    float* tp = tile + node_l * 16 + 4 * q;
    tp[0] = a0 * d; tp[1] = a1 * d; tp[2] = a2 * d; tp[3] = a3 * d;
  }
  __syncthreads();
  int base = blockIdx.x * 128;
  for (int idx = t; idx < 128 * 64; idx += 512) {
    int r = idx >> 6, jj = idx & 63;
    int onode = base + r;
    if (onode < n) {
      float o = b2s[jj];
      #pragma unroll
      for (int k = 0; k < 16; k++) o = fmaf(tile[r * 16 + k], w2s[k * 64 + jj], o);
      out[(size_t)onode * 64 + jj] = o;
    }
  }
}

extern "C" void kernel_launch(void* const* d_in, const int* in_sizes, int n_in,
                              void* d_out, int out_size, void* d_ws, size_t ws_size,
                              hipStream_t stream) {
  const float* x = (const float*)d_in[0];
  const int* ei = (const int*)d_in[1];   // int32 (JAX x64 disabled)
  const float* W1 = (const float*)d_in[2];
  const float* b1 = (const float*)d_in[3];
  const float* W2 = (const float*)d_in[4];
  const float* b2 = (const float*)d_in[5];
  float* out = (float*)d_out;

  int n = in_sizes[0] / 128;   // 100000
  int e = in_sizes[1] / 2;     // 3200000
  const int* row = ei;         // sources
  const int* col = ei + e;     // targets (aggregation index)

  int nb = (n + 1023) / 1024;            // scan blocks (98)
  int nb3 = (n + 1024) / 1024;           // covers sentinel i==n
  int npad = ((n + 1 + 1023) / 1024) * 1024;  // 100352: aligned region size

  // workspace layout (ints; even counts keep 8B alignment for the fp16 tables)
  int* deg = (int*)d_ws;                 // npad
  int* node_start = deg + npad;          // npad (holds n+1 entries)
  int* cur = node_start + npad;          // npad
  int* bsum = cur + npad;                // 1024
  int* pairs = bsum + 1024;              // e (12.8 MB)
  __half* s1 = (__half*)(pairs + e);     // 16n halfs = 3.2 MB
  __half* s2 = s1 + (size_t)n * 16;      // 16n halfs = 3.2 MB
  float* dinv = (float*)(s2 + (size_t)n * 16);  // n floats

  int g4 = ((e >> 2) + 255) / 256;       // 3125 blocks for edge passes

  // ---- node-grouped edge build: hist -> scan -> one-pass scatter ----
  zero_i_kernel<<<(n + 511) / 512, 512, 0, stream>>>(deg, n);
  histN_kernel<<<g4, 256, 0, stream>>>(col, deg, e);
  scan1_kernel<<<nb, 1024, 0, stream>>>(deg, node_start, bsum, n);
  scan2_kernel<<<1, 1024, 0, stream>>>(bsum, nb);
  scan3_kernel<<<nb3, 1024, 0, stream>>>(node_start, bsum, deg, cur, dinv, n, e);
  scatter_kernel<<<g4, 256, 0, stream>>>(row, col, cur, pairs, e);

  // ---- layer 1: transform (128->16) -> fp16 table, run-gather aggregate ----
  mm1_kernel<<<(n + NODES_PER_BLOCK - 1) / NODES_PER_BLOCK, 256, 0, stream>>>(x, W1, dinv, s1, n);
  agg1_kernel<<<(n + 127) / 128, 512, 0, stream>>>(pairs, node_start, s1, dinv, b1, s2, n);

  // ---- layer 2: run-gather aggregate + fused 16->64 transform ----
  agg2_kernel<<<(n + 127) / 128, 512, 0, stream>>>(pairs, node_start, s2, dinv, W2, b2, out, n);
}